// Round 1
// baseline (228.671 us; speedup 1.0000x reference)
//
#include <hip/hip_runtime.h>
#include <hip/hip_bf16.h>

#define N 8192
#define OD 64
#define E_EDGES 262144

#define BM 64
#define BK 64
#define KSPLIT 8
#define LDSS 72   // LDS row stride in bf16 elements: 144 B, keeps 16B alignment, spreads banks

typedef __attribute__((ext_vector_type(8))) short bf16x8;
typedef __attribute__((ext_vector_type(4))) float f32x4;

__device__ __forceinline__ unsigned short f2bf(float f) {
    union { float f; unsigned u; } v; v.f = f;
    // round-to-nearest-even to bf16
    unsigned r = (v.u + 0x7fffu + ((v.u >> 16) & 1u)) >> 16;
    return (unsigned short)r;
}

// ---------------- Kernel 1: sum of squares of attn -> ws[0] ----------------
__global__ __launch_bounds__(256) void norm_sq_kernel(const float* __restrict__ attn,
                                                      float* __restrict__ ws) {
    const float4* a4 = (const float4*)attn;
    const int total = (N * (long)N) / 4;  // 16,777,216 float4s
    float s = 0.f;
    for (long i = (long)blockIdx.x * blockDim.x + threadIdx.x; i < total;
         i += (long)gridDim.x * blockDim.x) {
        float4 v = a4[i];
        s += v.x * v.x + v.y * v.y + v.z * v.z + v.w * v.w;
    }
    for (int off = 32; off > 0; off >>= 1) s += __shfl_down(s, off, 64);
    __shared__ float wpart[4];
    int wid = threadIdx.x >> 6;
    if ((threadIdx.x & 63) == 0) wpart[wid] = s;
    __syncthreads();
    if (threadIdx.x == 0) {
        atomicAdd(ws, wpart[0] + wpart[1] + wpart[2] + wpart[3]);
    }
}

// ---------------- Kernel 2: y += x[:, kslice] @ W[kslice, :]  (bf16 MFMA) ----------------
__global__ __launch_bounds__(256) void gemm_kernel(const float* __restrict__ x,
                                                   const float* __restrict__ w,
                                                   float* __restrict__ y) {
    __shared__ unsigned short xs[BM * LDSS];   // x tile, row-major [row][k]
    __shared__ unsigned short wsh[OD * LDSS];  // W tile, TRANSPOSED [col][k]

    const int tid = threadIdx.x;
    const int row0 = blockIdx.x * BM;
    const int k0base = blockIdx.y * (N / KSPLIT);
    const int wv = tid >> 6;
    const int lane = tid & 63;
    const int lrow = lane & 15;   // M-row / N-col within 16x16 fragment
    const int g = lane >> 4;      // k-group

    f32x4 acc[4] = {f32x4{0,0,0,0}, f32x4{0,0,0,0}, f32x4{0,0,0,0}, f32x4{0,0,0,0}};

    for (int kc = 0; kc < (N / KSPLIT) / BK; ++kc) {  // 16 chunks of BK=64
        const int k0 = k0base + kc * BK;
        __syncthreads();
        // stage x tile: BM x BK f32 -> bf16 LDS (coalesced float4 loads)
        #pragma unroll
        for (int p = 0; p < 4; ++p) {
            int idx = p * 1024 + tid * 4;
            int r = idx >> 6, c = idx & 63;
            float4 v = *(const float4*)(&x[(row0 + r) * N + k0 + c]);
            ushort4 b;
            b.x = f2bf(v.x); b.y = f2bf(v.y); b.z = f2bf(v.z); b.w = f2bf(v.w);
            *(ushort4*)(&xs[r * LDSS + c]) = b;
        }
        // stage W tile transposed: global [k][64] -> LDS [col][k]
        #pragma unroll
        for (int p = 0; p < 4; ++p) {
            int idx = p * 1024 + tid * 4;
            int kk = idx >> 6, j = idx & 63;
            float4 v = *(const float4*)(&w[(k0 + kk) * OD + j]);
            wsh[(j + 0) * LDSS + kk] = f2bf(v.x);
            wsh[(j + 1) * LDSS + kk] = f2bf(v.y);
            wsh[(j + 2) * LDSS + kk] = f2bf(v.z);
            wsh[(j + 3) * LDSS + kk] = f2bf(v.w);
        }
        __syncthreads();
        // compute: wave wv owns rows [wv*16, wv*16+16), all 64 cols (4 col-frags)
        const int r = wv * 16 + lrow;
        #pragma unroll
        for (int ks = 0; ks < 2; ++ks) {
            bf16x8 a = *(const bf16x8*)(&xs[r * LDSS + ks * 32 + g * 8]);
            #pragma unroll
            for (int cf = 0; cf < 4; ++cf) {
                bf16x8 b = *(const bf16x8*)(&wsh[(cf * 16 + lrow) * LDSS + ks * 32 + g * 8]);
                acc[cf] = __builtin_amdgcn_mfma_f32_16x16x32_bf16(a, b, acc[cf], 0, 0, 0);
            }
        }
    }
    // epilogue: C/D layout col=lane&15, row=(lane>>4)*4+i  (verified m89)
    #pragma unroll
    for (int cf = 0; cf < 4; ++cf) {
        #pragma unroll
        for (int i = 0; i < 4; ++i) {
            int rr = row0 + wv * 16 + g * 4 + i;
            int cc = cf * 16 + lrow;
            atomicAdd(&y[rr * OD + cc], acc[cf][i]);
        }
    }
}

// ---------------- Kernel 3: edge scatter: out[row[e]] += values[e]*attn[row,col] * y[col[e]] ----------------
__global__ __launch_bounds__(256) void scatter_kernel(const float* __restrict__ values,
                                                      const float* __restrict__ attn,
                                                      const int* __restrict__ row,
                                                      const int* __restrict__ col,
                                                      const float* __restrict__ y,
                                                      float* __restrict__ out) {
    const int e = blockIdx.x * 4 + (threadIdx.x >> 6);
    const int lane = threadIdx.x & 63;
    const int r = row[e];
    const int c = col[e];
    const float ev = values[e] * attn[r * N + c];
    atomicAdd(&out[r * OD + lane], ev * y[c * OD + lane]);
}

// ---------------- Kernel 4: finalize norm ----------------
__global__ void finalize_kernel(const float* __restrict__ ws, float* __restrict__ out_norm) {
    if (threadIdx.x == 0) *out_norm = sqrtf(ws[0]);
}

extern "C" void kernel_launch(void* const* d_in, const int* in_sizes, int n_in,
                              void* d_out, int out_size, void* d_ws, size_t ws_size,
                              hipStream_t stream) {
    const float* x      = (const float*)d_in[0];
    const float* attn   = (const float*)d_in[1];
    const float* weight = (const float*)d_in[2];
    const float* values = (const float*)d_in[3];
    const int*   row    = (const int*)d_in[4];
    const int*   col    = (const int*)d_in[5];
    float* out = (float*)d_out;
    float* wsf = (float*)d_ws;
    float* y = wsf + 64;  // y at +256 B, [N][OD] f32 = 2 MB

    // zero: out (atomic target), ws norm-acc + y partial buffer
    hipMemsetAsync(d_out, 0, (size_t)out_size * sizeof(float), stream);
    hipMemsetAsync(d_ws, 0, 256 + (size_t)N * OD * sizeof(float), stream);

    norm_sq_kernel<<<2048, 256, 0, stream>>>(attn, wsf);
    gemm_kernel<<<dim3(N / BM, KSPLIT), 256, 0, stream>>>(x, weight, y);
    scatter_kernel<<<E_EDGES / 4, 256, 0, stream>>>(values, attn, row, col, y, out);
    finalize_kernel<<<1, 64, 0, stream>>>(wsf, out + (size_t)N * OD);
}